// Round 2
// baseline (173.877 us; speedup 1.0000x reference)
//
#include <hip/hip_runtime.h>
#include <hip/hip_bf16.h>

#ifndef __has_builtin
#define __has_builtin(x) 0
#endif

__device__ __forceinline__ float fast_exp2(float x) {
#if __has_builtin(__builtin_amdgcn_exp2f)
  return __builtin_amdgcn_exp2f(x);
#else
  return exp2f(x);
#endif
}
__device__ __forceinline__ float fast_rcp(float x) {
#if __has_builtin(__builtin_amdgcn_rcpf)
  return __builtin_amdgcn_rcpf(x);
#else
  return 1.0f / x;
#endif
}

constexpr int Bsz = 8, QL = 128, KL = 512, DD = 256, UU = 256;
constexpr int QB = 2;                    // q rows per block in attn kernel
constexpr int PR = 8;                    // rows per proj block
constexpr float NEG_INF = -1e6f;
constexpr float C2 = 2.885390081777927f; // 2*log2(e): exp2(C2*x) == exp(2x)

// ---------------------------------------------------------------------------
// Kernel 1: projections, pre-scaled by C2. 8 rows/block, thread = u.
//   qp[b][q][u]  = C2 * sum_d query[b,q,d] * Wq[d,u]   ([B,Q,U])
//   kpT[b][u][k] = C2 * sum_d key[b,k,d]   * Wk[d,u]   ([B,U,K], transposed)
// Key blocks whose k-range is entirely masked (k0 >= valid_len[b]) exit early
// (attn never reads masked kpT).
// ---------------------------------------------------------------------------
__global__ __launch_bounds__(256) void proj_kernel(
    const float* __restrict__ query, const float* __restrict__ key,
    const float* __restrict__ Wq, const float* __restrict__ Wk,
    const int* __restrict__ valid_len,
    float* __restrict__ qp, float* __restrict__ kpT)
{
  const int u   = threadIdx.x;
  const int blk = blockIdx.x;
  constexpr int QBLKS = Bsz * QL / PR;   // 128
  const bool isQ = blk < QBLKS;
  const int  m0  = isQ ? blk * PR : (blk - QBLKS) * PR;

  int b = 0, k0 = 0;
  if (!isQ) {
    b = m0 / KL; k0 = m0 % KL;
    if (k0 >= valid_len[b]) return;      // fully masked key rows: kpT unread
  }
  const float* __restrict__ in = isQ ? query : key;
  const float* __restrict__ W  = isQ ? Wq : Wk;
  const float* r0 = in + (size_t)m0 * DD;

  float acc[PR];
#pragma unroll
  for (int r = 0; r < PR; ++r) acc[r] = 0.f;

  for (int d = 0; d < DD; d += 4) {
    const float w0 = W[(d + 0) * UU + u];
    const float w1 = W[(d + 1) * UU + u];
    const float w2 = W[(d + 2) * UU + u];
    const float w3 = W[(d + 3) * UU + u];
#pragma unroll
    for (int r = 0; r < PR; ++r) {
      const float4 rv = *reinterpret_cast<const float4*>(r0 + r * DD + d);
      acc[r] = fmaf(rv.x, w0, fmaf(rv.y, w1, fmaf(rv.z, w2, fmaf(rv.w, w3, acc[r]))));
    }
  }

  if (isQ) {
    float* o = qp + (size_t)m0 * UU + u;
#pragma unroll
    for (int r = 0; r < PR; ++r) o[r * UU] = acc[r] * C2;
  } else {
    float* o = kpT + ((size_t)b * UU + u) * KL + k0;
    *reinterpret_cast<float4*>(o) =
        make_float4(acc[0] * C2, acc[1] * C2, acc[2] * C2, acc[3] * C2);
    *reinterpret_cast<float4*>(o + 4) =
        make_float4(acc[4] * C2, acc[5] * C2, acc[6] * C2, acc[7] * C2);
  }
}

// ---------------------------------------------------------------------------
// Kernel 2: scores (tanh contraction) + masked softmax + attn@V.
// Block = (b, QB=2 q-rows), 512 blocks (2/CU), 256 threads; thread t owns
// k = {2t, 2t+1}. Waves with k-range fully >= valid_len skip the u-loop
// (their scores are exactly NEG_INF -> attn weight 0). Epilogue bounded by
// valid_len (attn weights beyond it are 0).
// score[q][k] = Vsum - sum_u 2*v_w[u] * rcp(1 + exp2(qp[q][u] + kpT[u][k]))
// ---------------------------------------------------------------------------
__global__ __launch_bounds__(256) void attn_kernel(
    const float* __restrict__ value, const int* __restrict__ valid_len,
    const float* __restrict__ v_w, const float* __restrict__ qp,
    const float* __restrict__ kpT, float* __restrict__ out)
{
  __shared__ __align__(16) float sc[QB][KL];   // attn weights (4 KB)
  __shared__ float qp_s[QB][UU];               // 2 KB
  __shared__ float w2_s[UU];                   // 1 KB
  __shared__ float red_s[4][QB];

  const int t    = threadIdx.x;
  const int lane = t & 63, wave = t >> 6;
  const int blk  = blockIdx.x;
  const int b    = blk / (QL / QB);
  const int q0   = (blk % (QL / QB)) * QB;
  const int vlen = valid_len[b];

  // ---- stage qp rows + 2*v_w into LDS; block-reduce Vsum = sum(v_w) ----
  const float vw = v_w[t];
  w2_s[t] = 2.0f * vw;
#pragma unroll
  for (int q = 0; q < QB; ++q)
    qp_s[q][t] = qp[(size_t)(b * QL + q0 + q) * UU + t];

  float s = vw;
#pragma unroll
  for (int off = 32; off >= 1; off >>= 1) s += __shfl_xor(s, off, 64);
  if (lane == 0) red_s[wave][0] = s;
  __syncthreads();
  const float vsum = red_s[0][0] + red_s[1][0] + red_s[2][0] + red_s[3][0];
  __syncthreads();

  // ---- score accumulation over u (skipped entirely by fully-masked waves) --
  const int k2 = 2 * t;
  float acc[QB][2];
#pragma unroll
  for (int q = 0; q < QB; ++q) { acc[q][0] = 0.f; acc[q][1] = 0.f; }

  if (k2 < vlen) {
    const float2* __restrict__ kp2 =
        reinterpret_cast<const float2*>(kpT + (size_t)b * UU * KL);
#pragma unroll 2
    for (int u = 0; u < UU; ++u) {
      const float2 kv = kp2[u * (KL / 2) + t];
      const float w2 = w2_s[u];
#pragma unroll
      for (int q = 0; q < QB; ++q) {
        const float qv = qp_s[q][u];
        const float e0 = fast_exp2(qv + kv.x);   // = exp(2x), inputs pre-scaled
        const float e1 = fast_exp2(qv + kv.y);
        const float r0 = fast_rcp(1.0f + e0);    // tanh(x) = 1 - 2*r
        const float r1 = fast_rcp(1.0f + e1);
        acc[q][0] = fmaf(w2, r0, acc[q][0]);
        acc[q][1] = fmaf(w2, r1, acc[q][1]);
      }
    }
  }

  // ---- mask + softmax over k ----
  float sr[QB][2], lmax[QB];
#pragma unroll
  for (int q = 0; q < QB; ++q) {
    sr[q][0] = (k2     < vlen) ? (vsum - acc[q][0]) : NEG_INF;
    sr[q][1] = (k2 + 1 < vlen) ? (vsum - acc[q][1]) : NEG_INF;
    lmax[q] = fmaxf(sr[q][0], sr[q][1]);
  }
#pragma unroll
  for (int off = 32; off >= 1; off >>= 1) {
#pragma unroll
    for (int q = 0; q < QB; ++q)
      lmax[q] = fmaxf(lmax[q], __shfl_xor(lmax[q], off, 64));
  }
  if (lane == 0) {
#pragma unroll
    for (int q = 0; q < QB; ++q) red_s[wave][q] = lmax[q];
  }
  __syncthreads();
  float mq[QB];
#pragma unroll
  for (int q = 0; q < QB; ++q)
    mq[q] = fmaxf(fmaxf(red_s[0][q], red_s[1][q]), fmaxf(red_s[2][q], red_s[3][q]));
  __syncthreads();

  float ex[QB][2], lsum[QB];
#pragma unroll
  for (int q = 0; q < QB; ++q) {
    ex[q][0] = __expf(sr[q][0] - mq[q]);   // masked -> 0, same as ref
    ex[q][1] = __expf(sr[q][1] - mq[q]);
    lsum[q] = ex[q][0] + ex[q][1];
  }
#pragma unroll
  for (int off = 32; off >= 1; off >>= 1) {
#pragma unroll
    for (int q = 0; q < QB; ++q) lsum[q] += __shfl_xor(lsum[q], off, 64);
  }
  if (lane == 0) {
#pragma unroll
    for (int q = 0; q < QB; ++q) red_s[wave][q] = lsum[q];
  }
  __syncthreads();
#pragma unroll
  for (int q = 0; q < QB; ++q) {
    const float tot = red_s[0][q] + red_s[1][q] + red_s[2][q] + red_s[3][q];
    const float inv = fast_rcp(tot);       // tot >= 1 (max term contributes 1)
    sc[q][k2]     = ex[q][0] * inv;
    sc[q][k2 + 1] = ex[q][1] * inv;
  }
  __syncthreads();

  // ---- out[b,q,d] = sum_{k < vlen} attn[q][k] * value[b,k,d]; thread = d ----
  const int kmax = (vlen + 3) & ~3;        // sc beyond vlen is exactly 0
  const float* __restrict__ vb = value + (size_t)b * KL * DD;
  float ov[QB];
#pragma unroll
  for (int q = 0; q < QB; ++q) ov[q] = 0.f;
  for (int k = 0; k < kmax; k += 4) {
    const float v0 = vb[(k + 0) * DD + t];
    const float v1 = vb[(k + 1) * DD + t];
    const float v2 = vb[(k + 2) * DD + t];
    const float v3 = vb[(k + 3) * DD + t];
#pragma unroll
    for (int q = 0; q < QB; ++q) {
      const float4 a = *reinterpret_cast<const float4*>(&sc[q][k]);
      ov[q] = fmaf(a.x, v0, fmaf(a.y, v1, fmaf(a.z, v2, fmaf(a.w, v3, ov[q]))));
    }
  }
#pragma unroll
  for (int q = 0; q < QB; ++q)
    out[(size_t)(b * QL + q0 + q) * DD + t] = ov[q];
}

extern "C" void kernel_launch(void* const* d_in, const int* in_sizes, int n_in,
                              void* d_out, int out_size, void* d_ws, size_t ws_size,
                              hipStream_t stream) {
  const float* query     = (const float*)d_in[0];
  const float* key       = (const float*)d_in[1];
  const float* value     = (const float*)d_in[2];
  const int*   valid_len = (const int*)d_in[3];
  const float* Wq        = (const float*)d_in[4];
  const float* Wk        = (const float*)d_in[5];
  const float* v_w       = (const float*)d_in[6];
  float* out = (float*)d_out;

  float* qp  = (float*)d_ws;                       // B*QL*UU floats (1 MB)
  float* kpT = qp + (size_t)Bsz * QL * UU;         // B*UU*KL floats (4 MB)

  const int proj_blocks = (Bsz * QL + Bsz * KL) / PR;   // 128 + 512 = 640
  proj_kernel<<<proj_blocks, 256, 0, stream>>>(query, key, Wq, Wk, valid_len, qp, kpT);

  const int attn_blocks = Bsz * (QL / QB);              // 512
  attn_kernel<<<attn_blocks, 256, 0, stream>>>(value, valid_len, v_w, qp, kpT, out);
}

// Round 3
// 147.777 us; speedup vs baseline: 1.1766x; 1.1766x over previous
//
#include <hip/hip_runtime.h>
#include <hip/hip_bf16.h>

#ifndef __has_builtin
#define __has_builtin(x) 0
#endif

__device__ __forceinline__ float fast_exp2(float x) {
#if __has_builtin(__builtin_amdgcn_exp2f)
  return __builtin_amdgcn_exp2f(x);
#else
  return exp2f(x);
#endif
}
__device__ __forceinline__ float fast_rcp(float x) {
#if __has_builtin(__builtin_amdgcn_rcpf)
  return __builtin_amdgcn_rcpf(x);
#else
  return 1.0f / x;
#endif
}

constexpr int Bsz = 8, QL = 128, KL = 512, DD = 256, UU = 256;
constexpr int QB = 2;                    // q rows per attn block
constexpr int PR = 8;                    // rows per proj block
constexpr int DT = 8;                    // d-chunk in proj pipeline
constexpr int UT = 8;                    // u-tile in attn pipeline
constexpr float NEG_INF = -1e6f;
constexpr float C2 = 2.885390081777927f; // 2*log2(e): exp2(C2*x) == exp(2x)

// ---------------------------------------------------------------------------
// Kernel 1: projections, pre-scaled by C2, register-double-buffered over d.
//   qp[b][q][u]  = C2 * sum_d query[b,q,d] * Wq[d,u]   ([B,Q,U])
//   kpT[b][u][k] = C2 * sum_d key[b,k,d]   * Wk[d,u]   ([B,U,K], transposed)
// thread = u; 8 rows/block. W loads coalesced (prefetched 1 chunk ahead);
// row loads wave-uniform (L1). Fully-masked key blocks exit early.
// ---------------------------------------------------------------------------
__global__ __launch_bounds__(256) void proj_kernel(
    const float* __restrict__ query, const float* __restrict__ key,
    const float* __restrict__ Wq, const float* __restrict__ Wk,
    const int* __restrict__ valid_len,
    float* __restrict__ qp, float* __restrict__ kpT)
{
  const int u   = threadIdx.x;
  const int blk = blockIdx.x;
  constexpr int QBLKS = Bsz * QL / PR;   // 128
  const bool isQ = blk < QBLKS;
  const int  m0  = isQ ? blk * PR : (blk - QBLKS) * PR;

  int b = 0, k0 = 0;
  if (!isQ) {
    b = m0 / KL; k0 = m0 % KL;
    if (k0 >= valid_len[b]) return;      // masked rows never read by attn
  }
  const float* __restrict__ in = isQ ? query : key;
  const float* __restrict__ W  = isQ ? Wq : Wk;
  const float* r0 = in + (size_t)m0 * DD;

  float acc[PR];
#pragma unroll
  for (int r = 0; r < PR; ++r) acc[r] = 0.f;

  float  w_c[DT], w_n[DT];
  float4 r_c[PR][2], r_n[PR][2];

  // prologue: chunk d=0
#pragma unroll
  for (int j = 0; j < DT; ++j) w_c[j] = W[j * UU + u];
#pragma unroll
  for (int r = 0; r < PR; ++r) {
    r_c[r][0] = *reinterpret_cast<const float4*>(r0 + r * DD);
    r_c[r][1] = *reinterpret_cast<const float4*>(r0 + r * DD + 4);
  }

  for (int d = 0; d < DD; d += DT) {
    const int dn = (d + DT < DD) ? d + DT : 0;   // clamped dummy prefetch on last
    // issue next-chunk loads first (stay in flight during compute)
#pragma unroll
    for (int j = 0; j < DT; ++j) w_n[j] = W[(dn + j) * UU + u];
#pragma unroll
    for (int r = 0; r < PR; ++r) {
      r_n[r][0] = *reinterpret_cast<const float4*>(r0 + r * DD + dn);
      r_n[r][1] = *reinterpret_cast<const float4*>(r0 + r * DD + dn + 4);
    }
    // compute on current chunk
#pragma unroll
    for (int r = 0; r < PR; ++r) {
      float a = acc[r];
      a = fmaf(r_c[r][0].x, w_c[0], a);
      a = fmaf(r_c[r][0].y, w_c[1], a);
      a = fmaf(r_c[r][0].z, w_c[2], a);
      a = fmaf(r_c[r][0].w, w_c[3], a);
      a = fmaf(r_c[r][1].x, w_c[4], a);
      a = fmaf(r_c[r][1].y, w_c[5], a);
      a = fmaf(r_c[r][1].z, w_c[6], a);
      a = fmaf(r_c[r][1].w, w_c[7], a);
      acc[r] = a;
    }
    // rotate
#pragma unroll
    for (int j = 0; j < DT; ++j) w_c[j] = w_n[j];
#pragma unroll
    for (int r = 0; r < PR; ++r) { r_c[r][0] = r_n[r][0]; r_c[r][1] = r_n[r][1]; }
  }

  if (isQ) {
    float* o = qp + (size_t)m0 * UU + u;
#pragma unroll
    for (int r = 0; r < PR; ++r) o[r * UU] = acc[r] * C2;
  } else {
    float* o = kpT + ((size_t)b * UU + u) * KL + k0;
    *reinterpret_cast<float4*>(o) =
        make_float4(acc[0] * C2, acc[1] * C2, acc[2] * C2, acc[3] * C2);
    *reinterpret_cast<float4*>(o + 4) =
        make_float4(acc[4] * C2, acc[5] * C2, acc[6] * C2, acc[7] * C2);
  }
}

// ---------------------------------------------------------------------------
// Kernel 2: scores + masked softmax + attn@V. Block = (b, 2 q-rows); 512
// blocks; thread t owns k = {2t, 2t+1}. u-loop register-double-buffered in
// tiles of UT=8 (8 float2 loads in flight covering ~512cy of trans work).
// b = blk & 7 interleaves batches across CUs for vlen load balance.
// score[q][k] = Vsum - sum_u 2*v_w[u] * rcp(1 + exp2(qp[q][u] + kpT[u][k]))
// ---------------------------------------------------------------------------
__global__ __launch_bounds__(256) void attn_kernel(
    const float* __restrict__ value, const int* __restrict__ valid_len,
    const float* __restrict__ v_w, const float* __restrict__ qp,
    const float* __restrict__ kpT, float* __restrict__ out)
{
  __shared__ __align__(16) float sc[QB][KL];   // attn weights (4 KB)
  __shared__ float qp_s[QB][UU];               // 2 KB
  __shared__ float w2_s[UU];                   // 1 KB
  __shared__ float red_s[4][QB];

  const int t    = threadIdx.x;
  const int lane = t & 63, wave = t >> 6;
  const int blk  = blockIdx.x;
  const int b    = blk & 7;                    // batch-interleaved mapping
  const int q0   = (blk >> 3) * QB;
  const int vlen = valid_len[b];

  // ---- stage qp rows + 2*v_w into LDS; block-reduce Vsum = sum(v_w) ----
  const float vw = v_w[t];
  w2_s[t] = 2.0f * vw;
#pragma unroll
  for (int q = 0; q < QB; ++q)
    qp_s[q][t] = qp[(size_t)(b * QL + q0 + q) * UU + t];

  float s = vw;
#pragma unroll
  for (int off = 32; off >= 1; off >>= 1) s += __shfl_xor(s, off, 64);
  if (lane == 0) red_s[wave][0] = s;
  __syncthreads();
  const float vsum = red_s[0][0] + red_s[1][0] + red_s[2][0] + red_s[3][0];
  __syncthreads();

  // ---- score accumulation over u, software-pipelined ----
  const int k2 = 2 * t;
  float acc[QB][2];
#pragma unroll
  for (int q = 0; q < QB; ++q) { acc[q][0] = 0.f; acc[q][1] = 0.f; }

  if (k2 < vlen) {
    const float2* __restrict__ kp2 =
        reinterpret_cast<const float2*>(kpT + (size_t)b * UU * KL);
    float2 cur[UT], nxt[UT];
#pragma unroll
    for (int j = 0; j < UT; ++j) cur[j] = kp2[j * (KL / 2) + t];

    for (int u0 = 0; u0 < UU; u0 += UT) {
      const int un = (u0 + UT < UU) ? u0 + UT : 0;   // clamped dummy on last
#pragma unroll
      for (int j = 0; j < UT; ++j) nxt[j] = kp2[(un + j) * (KL / 2) + t];
#pragma unroll
      for (int j = 0; j < UT; ++j) {
        const float w2 = w2_s[u0 + j];
        const float kx = cur[j].x, ky = cur[j].y;
#pragma unroll
        for (int q = 0; q < QB; ++q) {
          const float qv = qp_s[q][u0 + j];
          const float e0 = fast_exp2(qv + kx);   // = exp(2x), inputs pre-scaled
          const float e1 = fast_exp2(qv + ky);
          const float r0 = fast_rcp(1.0f + e0); // tanh(x) = 1 - 2*r
          const float r1 = fast_rcp(1.0f + e1);
          acc[q][0] = fmaf(w2, r0, acc[q][0]);
          acc[q][1] = fmaf(w2, r1, acc[q][1]);
        }
      }
#pragma unroll
      for (int j = 0; j < UT; ++j) cur[j] = nxt[j];
    }
  }

  // ---- mask + softmax over k ----
  float sr[QB][2], lmax[QB];
#pragma unroll
  for (int q = 0; q < QB; ++q) {
    sr[q][0] = (k2     < vlen) ? (vsum - acc[q][0]) : NEG_INF;
    sr[q][1] = (k2 + 1 < vlen) ? (vsum - acc[q][1]) : NEG_INF;
    lmax[q] = fmaxf(sr[q][0], sr[q][1]);
  }
#pragma unroll
  for (int off = 32; off >= 1; off >>= 1) {
#pragma unroll
    for (int q = 0; q < QB; ++q)
      lmax[q] = fmaxf(lmax[q], __shfl_xor(lmax[q], off, 64));
  }
  if (lane == 0) {
#pragma unroll
    for (int q = 0; q < QB; ++q) red_s[wave][q] = lmax[q];
  }
  __syncthreads();
  float mq[QB];
#pragma unroll
  for (int q = 0; q < QB; ++q)
    mq[q] = fmaxf(fmaxf(red_s[0][q], red_s[1][q]), fmaxf(red_s[2][q], red_s[3][q]));
  __syncthreads();

  float ex[QB][2], lsum[QB];
#pragma unroll
  for (int q = 0; q < QB; ++q) {
    ex[q][0] = __expf(sr[q][0] - mq[q]);   // masked -> 0, matches ref
    ex[q][1] = __expf(sr[q][1] - mq[q]);
    lsum[q] = ex[q][0] + ex[q][1];
  }
#pragma unroll
  for (int off = 32; off >= 1; off >>= 1) {
#pragma unroll
    for (int q = 0; q < QB; ++q) lsum[q] += __shfl_xor(lsum[q], off, 64);
  }
  if (lane == 0) {
#pragma unroll
    for (int q = 0; q < QB; ++q) red_s[wave][q] = lsum[q];
  }
  __syncthreads();
#pragma unroll
  for (int q = 0; q < QB; ++q) {
    const float tot = red_s[0][q] + red_s[1][q] + red_s[2][q] + red_s[3][q];
    const float inv = fast_rcp(tot);       // tot >= 1 (max term contributes 1)
    sc[q][k2]     = ex[q][0] * inv;
    sc[q][k2 + 1] = ex[q][1] * inv;
  }
  __syncthreads();

  // ---- out[b,q,d] = sum_{k<vlen} attn[q][k]*value[b,k,d]; thread = d ------
  const int kmax = (vlen + 3) & ~3;        // sc beyond vlen is exactly 0
  const float* __restrict__ vb = value + (size_t)b * KL * DD;
  float ov[QB];
#pragma unroll
  for (int q = 0; q < QB; ++q) ov[q] = 0.f;

  float v_c[4], v_n[4];
#pragma unroll
  for (int j = 0; j < 4; ++j) v_c[j] = vb[j * DD + t];
  for (int k = 0; k < kmax; k += 4) {
    const int kn = (k + 4 < kmax) ? k + 4 : 0;
#pragma unroll
    for (int j = 0; j < 4; ++j) v_n[j] = vb[(kn + j) * DD + t];
#pragma unroll
    for (int q = 0; q < QB; ++q) {
      const float4 a = *reinterpret_cast<const float4*>(&sc[q][k]);
      ov[q] = fmaf(a.x, v_c[0], fmaf(a.y, v_c[1],
               fmaf(a.z, v_c[2], fmaf(a.w, v_c[3], ov[q]))));
    }
#pragma unroll
    for (int j = 0; j < 4; ++j) v_c[j] = v_n[j];
  }
#pragma unroll
  for (int q = 0; q < QB; ++q)
    out[(size_t)(b * QL + q0 + q) * DD + t] = ov[q];
}

extern "C" void kernel_launch(void* const* d_in, const int* in_sizes, int n_in,
                              void* d_out, int out_size, void* d_ws, size_t ws_size,
                              hipStream_t stream) {
  const float* query     = (const float*)d_in[0];
  const float* key       = (const float*)d_in[1];
  const float* value     = (const float*)d_in[2];
  const int*   valid_len = (const int*)d_in[3];
  const float* Wq        = (const float*)d_in[4];
  const float* Wk        = (const float*)d_in[5];
  const float* v_w       = (const float*)d_in[6];
  float* out = (float*)d_out;

  float* qp  = (float*)d_ws;                       // B*QL*UU floats (1 MB)
  float* kpT = qp + (size_t)Bsz * QL * UU;         // B*UU*KL floats (4 MB)

  const int proj_blocks = (Bsz * QL + Bsz * KL) / PR;   // 128 + 512 = 640
  proj_kernel<<<proj_blocks, 256, 0, stream>>>(query, key, Wq, Wk, valid_len, qp, kpT);

  const int attn_blocks = Bsz * (QL / QB);              // 512
  attn_kernel<<<attn_blocks, 256, 0, stream>>>(value, valid_len, v_w, qp, kpT, out);
}